// Round 1
// baseline (16190.771 us; speedup 1.0000x reference)
//
#include <hip/hip_runtime.h>
#include <math.h>

#define PIXN 4096

enum { ACT_NONE = 0, ACT_LRELU = 1 };

// ---------------- weight prep ----------------
// wT[(tap*CIN + ci)*COUT + co] = w[(co*CIN + ci)*9 + tap]
__global__ __launch_bounds__(256) void wtrans_k(const float* __restrict__ w,
                                                float* __restrict__ wT,
                                                int CINv, int COUTv, int total) {
  int idx = blockIdx.x * 256 + threadIdx.x;
  if (idx >= total) return;
  int co = idx % COUTv;
  int t = idx / COUTv;
  int ci = t % CINv;
  int tap = t / CINv;
  wT[idx] = w[(co * CINv + ci) * 9 + tap];
}

// wT[c*288 + m*96 + e] = wm[e*96 + c];  bT[m*96+e] = bm[e]
__global__ __launch_bounds__(256) void qkvprep_k(const float* __restrict__ wq,
                                                 const float* __restrict__ wk,
                                                 const float* __restrict__ wv,
                                                 const float* __restrict__ bq,
                                                 const float* __restrict__ bk,
                                                 const float* __restrict__ bv,
                                                 float* __restrict__ wT,
                                                 float* __restrict__ bT) {
  int idx = blockIdx.x * 256 + threadIdx.x;
  if (idx < 96 * 288) {
    int e288 = idx % 288;
    int c = idx / 288;
    int m = e288 / 96, e = e288 % 96;
    const float* wm = (m == 0) ? wq : (m == 1) ? wk : wv;
    wT[idx] = wm[e * 96 + c];
  }
  if (idx < 288) {
    int m = idx / 96, e = idx % 96;
    const float* bm = (m == 0) ? bq : (m == 1) ? bk : bv;
    bT[idx] = bm[e];
  }
}

// ---------------- direct 3x3 conv, NHWC activations ----------------
// Block: 256 threads = 64 pixels (one row) x 4 oc-slots. Grid: (64 rows, n_img).
// wT layout: [tap][cin][oc].  Optional dual input (channel concat A then B).
template <int CIN, int COUT, int ACT, bool IN_NCHW, bool OUT_NCHW>
__global__ __launch_bounds__(256) void conv3x3_k(
    const float* __restrict__ inA, long sA, int ldA,
    const float* __restrict__ inB, long sB, int ldB, int cinA,
    const float* __restrict__ wT, const float* __restrict__ bias,
    float* __restrict__ out, long sOut,
    const float* __restrict__ resid, long sRes) {
  constexpr int NOC4 = COUT / 4;
  constexpr int NPS = (NOC4 + 3) / 4;   // oc4 groups per slot (max)
  constexpr int NCHUNK = CIN / 16;
  const int y = blockIdx.x;
  const int img = blockIdx.y;
  const int tid = threadIdx.x;
  const int pix = tid & 63;
  const int slot = tid >> 6;

  __shared__ float lds[3 * 66 * 17];

  float acc[NPS][4];
#pragma unroll
  for (int j = 0; j < NPS; ++j) {
    int oc4 = slot + 4 * j;
#pragma unroll
    for (int k = 0; k < 4; ++k) acc[j][k] = (oc4 < NOC4) ? bias[oc4 * 4 + k] : 0.f;
  }

  for (int ch = 0; ch < NCHUNK; ++ch) {
    __syncthreads();
    if constexpr (IN_NCHW) {
      for (int i = tid; i < 16 * 198; i += 256) {
        int cin = i / 198;
        int pos = i - cin * 198;
        int r = pos / 66;
        int c = pos - r * 66;
        int yy = y + r - 1;
        int xx = c - 1;
        float v = 0.f;
        if ((unsigned)yy < 64u && (unsigned)xx < 64u)
          v = inA[img * sA + (long)(ch * 16 + cin) * PIXN + yy * 64 + xx];
        lds[pos * 17 + cin] = v;
      }
    } else {
      for (int i = tid; i < 4 * 198; i += 256) {
        int c4 = i & 3;
        int pos = i >> 2;
        int r = pos / 66;
        int c = pos - r * 66;
        int yy = y + r - 1;
        int xx = c - 1;
        float4 v = make_float4(0.f, 0.f, 0.f, 0.f);
        int cing = ch * 16 + c4 * 4;
        if ((unsigned)yy < 64u && (unsigned)xx < 64u) {
          const float* src;
          if (cing < cinA)
            src = inA + img * sA + (long)(yy * 64 + xx) * ldA + cing;
          else
            src = inB + img * sB + (long)(yy * 64 + xx) * ldB + (cing - cinA);
          v = *reinterpret_cast<const float4*>(src);
        }
        int base = pos * 17 + c4 * 4;
        lds[base] = v.x; lds[base + 1] = v.y; lds[base + 2] = v.z; lds[base + 3] = v.w;
      }
    }
    __syncthreads();
#pragma unroll
    for (int r = 0; r < 3; ++r) {
#pragma unroll
      for (int kx = 0; kx < 3; ++kx) {
        const float* wp = wT + (long)((r * 3 + kx) * CIN + ch * 16) * COUT + slot * 4;
        const int lbase = (r * 66 + pix + kx) * 17;
#pragma unroll 4
        for (int cin = 0; cin < 16; ++cin) {
          float xv = lds[lbase + cin];
          const float* wpc = wp + cin * COUT;
#pragma unroll
          for (int j = 0; j < NPS; ++j) {
            if (slot + 4 * j < NOC4) {
              float4 w4 = *reinterpret_cast<const float4*>(wpc + j * 16);
              acc[j][0] = fmaf(xv, w4.x, acc[j][0]);
              acc[j][1] = fmaf(xv, w4.y, acc[j][1]);
              acc[j][2] = fmaf(xv, w4.z, acc[j][2]);
              acc[j][3] = fmaf(xv, w4.w, acc[j][3]);
            }
          }
        }
      }
    }
  }

  const int p = y * 64 + pix;
#pragma unroll
  for (int j = 0; j < NPS; ++j) {
    int oc4 = slot + 4 * j;
    if (oc4 >= NOC4) continue;
    float vv[4] = {acc[j][0], acc[j][1], acc[j][2], acc[j][3]};
    if (ACT == ACT_LRELU) {
#pragma unroll
      for (int k = 0; k < 4; ++k) vv[k] = vv[k] >= 0.f ? vv[k] : 0.1f * vv[k];
    }
    if constexpr (OUT_NCHW) {
      int oc = oc4 * 4;
#pragma unroll
      for (int k = 0; k < 4; ++k) {
        long o = img * sOut + (long)(oc + k) * PIXN + p;
        float rsd = resid[img * sRes + (long)(oc + k) * PIXN + p];
        out[o] = vv[k] + rsd;
      }
    } else {
      float4 v = make_float4(vv[0], vv[1], vv[2], vv[3]);
      *reinterpret_cast<float4*>(out + img * sOut + (long)p * COUT + oc4 * 4) = v;
    }
  }
}

// ---------------- 1x1 qkv projection: (12,4096,96) -> (12,4096,288) ----------------
__global__ __launch_bounds__(256) void gemm1x1_k(const float* __restrict__ in,
                                                 const float* __restrict__ wT,
                                                 const float* __restrict__ bias,
                                                 float* __restrict__ out) {
  const int pc = blockIdx.x;   // pixel chunk (64 px)
  const int img = blockIdx.y;
  const int tid = threadIdx.x;
  const int pix = tid & 63;
  const int slot = tid >> 6;
  __shared__ float lds[64 * 97];
  for (int i = tid; i < 64 * 24; i += 256) {
    int pi = i / 24, c4 = i - pi * 24;
    float4 v = *reinterpret_cast<const float4*>(
        in + ((long)img * PIXN + pc * 64 + pi) * 96 + c4 * 4);
    int base = pi * 97 + c4 * 4;
    lds[base] = v.x; lds[base + 1] = v.y; lds[base + 2] = v.z; lds[base + 3] = v.w;
  }
  __syncthreads();
  float acc[18][4];
#pragma unroll
  for (int j = 0; j < 18; ++j)
#pragma unroll
    for (int k = 0; k < 4; ++k) acc[j][k] = bias[(slot + 4 * j) * 4 + k];
  for (int c = 0; c < 96; ++c) {
    float xv = lds[pix * 97 + c];
    const float* wp = wT + c * 288 + slot * 4;
#pragma unroll
    for (int j = 0; j < 18; ++j) {
      float4 w4 = *reinterpret_cast<const float4*>(wp + j * 16);
      acc[j][0] = fmaf(xv, w4.x, acc[j][0]);
      acc[j][1] = fmaf(xv, w4.y, acc[j][1]);
      acc[j][2] = fmaf(xv, w4.z, acc[j][2]);
      acc[j][3] = fmaf(xv, w4.w, acc[j][3]);
    }
  }
  float* orow = out + ((long)img * PIXN + pc * 64 + pix) * 288;
#pragma unroll
  for (int j = 0; j < 18; ++j) {
    float4 v = make_float4(acc[j][0], acc[j][1], acc[j][2], acc[j][3]);
    *reinterpret_cast<float4*>(orow + (slot + 4 * j) * 4) = v;
  }
}

// ---------------- fused deformable sample + top2 attention ----------------
// s_om: [0..71]=off_y (g*9+n), [72..143]=off_x, [144..215]=sigmoid mask
__device__ __forceinline__ float dsampK(const float* __restrict__ kimg,
                                        const float* __restrict__ s_om,
                                        int g, int n, int y, int x, int c) {
  float oy = s_om[g * 9 + n];
  float ox = s_om[72 + g * 9 + n];
  float m = s_om[144 + g * 9 + n];
  float py = oy + (float)(y + n / 3 - 1);
  float px = ox + (float)(x + n % 3 - 1);
  float y0 = floorf(py), x0 = floorf(px);
  float wy = py - y0, wx = px - x0;
  float acc = 0.f;
#pragma unroll
  for (int dy = 0; dy < 2; ++dy) {
#pragma unroll
    for (int dx = 0; dx < 2; ++dx) {
      float yc = y0 + dy, xc = x0 + dx;
      if (yc >= 0.f && yc < 64.f && xc >= 0.f && xc < 64.f) {
        float w = (dy ? wy : 1.f - wy) * (dx ? wx : 1.f - wx);
        acc = fmaf(w, kimg[(long)((int)yc * 64 + (int)xc) * 288 + 96 + c], acc);
      }
    }
  }
  return acc * m;
}

__device__ __forceinline__ float2 dsamp2(const float* __restrict__ kimg,
                                         const float* __restrict__ s_om,
                                         int g, int n, int y, int x, int c) {
  float oy = s_om[g * 9 + n];
  float ox = s_om[72 + g * 9 + n];
  float m = s_om[144 + g * 9 + n];
  float py = oy + (float)(y + n / 3 - 1);
  float px = ox + (float)(x + n % 3 - 1);
  float y0 = floorf(py), x0 = floorf(px);
  float wy = py - y0, wx = px - x0;
  float aK = 0.f, aV = 0.f;
#pragma unroll
  for (int dy = 0; dy < 2; ++dy) {
#pragma unroll
    for (int dx = 0; dx < 2; ++dx) {
      float yc = y0 + dy, xc = x0 + dx;
      if (yc >= 0.f && yc < 64.f && xc >= 0.f && xc < 64.f) {
        float w = (dy ? wy : 1.f - wy) * (dx ? wx : 1.f - wx);
        const float* pp = kimg + (long)((int)yc * 64 + (int)xc) * 288 + 96 + c;
        aK = fmaf(w, pp[0], aK);
        aV = fmaf(w, pp[96], aV);
      }
    }
  }
  return make_float2(aK * m, aV * m);
}

__global__ __launch_bounds__(64) void attn_k(const float* __restrict__ qkv,
                                             int jj, int ii,
                                             const float* __restrict__ om,
                                             float* __restrict__ w_out,
                                             float* __restrict__ v_out) {
  const int bp = blockIdx.x;      // b*4096 + p
  const int b = bp >> 12;
  const int p = bp & 4095;
  const int y = p >> 6, x = p & 63;
  const int lane = threadIdx.x;
  __shared__ float s_om[216];
  const float* omrow = om + (long)bp * 216;
  for (int i = lane; i < 216; i += 64) {
    float v = omrow[i];
    if (i >= 144) v = 1.f / (1.f + expf(-v));
    s_om[i] = v;
  }
  __syncthreads();
  const float* qrow = qkv + ((long)(b * 3 + jj) * PIXN + p) * 288;
  const float* kimg = qkv + (long)(b * 3 + ii) * PIXN * 288;
  float q0 = qrow[lane];
  float q1 = 0.f;
  if (lane < 32) q1 = qrow[64 + lane];
  const int c0 = lane, g0 = lane / 12;
  const int c1 = 64 + lane, g1 = (64 + lane) / 12;

  float rel[9];
#pragma unroll
  for (int n = 0; n < 9; ++n) {
    float part = q0 * dsampK(kimg, s_om, g0, n, y, x, c0);
    if (lane < 32) part = fmaf(q1, dsampK(kimg, s_om, g1, n, y, x, c1), part);
#pragma unroll
    for (int off = 32; off > 0; off >>= 1) part += __shfl_xor(part, off, 64);
    rel[n] = part;
  }
  // top-2 (first index wins ties, matching jax.lax.top_k)
  int i0 = 0; float v0 = rel[0];
#pragma unroll
  for (int n = 1; n < 9; ++n) if (rel[n] > v0) { v0 = rel[n]; i0 = n; }
  int i1 = 0; float v1 = -3.4e38f;
#pragma unroll
  for (int n = 0; n < 9; ++n) if (n != i0 && rel[n] > v1) { v1 = rel[n]; i1 = n; }
  float e = expf(v1 - v0);
  float cw0 = 1.f / (1.f + e);
  float cw1 = e * cw0;

  float2 a0 = dsamp2(kimg, s_om, g0, i0, y, x, c0);
  float2 a1 = dsamp2(kimg, s_om, g0, i1, y, x, c0);
  float kup = cw0 * a0.x + cw1 * a1.x;
  float vre = cw0 * a0.y + cw1 * a1.y;
  float wpart = q0 * kup;
  v_out[(long)bp * 96 + c0] = vre;
  if (lane < 32) {
    float2 b0 = dsamp2(kimg, s_om, g1, i0, y, x, c1);
    float2 b1 = dsamp2(kimg, s_om, g1, i1, y, x, c1);
    float kup1 = cw0 * b0.x + cw1 * b1.x;
    float vre1 = cw0 * b0.y + cw1 * b1.y;
    wpart = fmaf(q1, kup1, wpart);
    v_out[(long)bp * 96 + c1] = vre1;
  }
#pragma unroll
  for (int off = 32; off > 0; off >>= 1) wpart += __shfl_xor(wpart, off, 64);
  if (lane == 0) w_out[bp] = wpart;
}

// ---------------- merge: softmax over the 2 source frames ----------------
__global__ __launch_bounds__(256) void merge_k(const float* __restrict__ w_buf,
                                               const float* __restrict__ vre,
                                               float* __restrict__ f_t) {
  long idx = (long)blockIdx.x * 256 + threadIdx.x;
  const long TOT = (long)4 * 3 * PIXN * 24;
  if (idx >= TOT) return;
  int c4 = idx % 24;
  long t = idx / 24;
  int p = t % PIXN;
  long t2 = t / PIXN;
  int jj = t2 % 3;
  int b = (int)(t2 / 3);
  long bpi = (long)b * PIXN + p;
  int pr0 = jj * 2, pr1 = jj * 2 + 1;
  float w0 = w_buf[(long)pr0 * 16384 + bpi];
  float w1 = w_buf[(long)pr1 * 16384 + bpi];
  float mx = fmaxf(w0, w1);
  float e0 = expf(w0 - mx), e1 = expf(w1 - mx);
  float inv = 1.f / (e0 + e1);
  float s0 = e0 * inv, s1 = e1 * inv;
  float4 va = *reinterpret_cast<const float4*>(vre + ((long)pr0 * 16384 + bpi) * 96 + c4 * 4);
  float4 vb = *reinterpret_cast<const float4*>(vre + ((long)pr1 * 16384 + bpi) * 96 + c4 * 4);
  float4 r;
  r.x = s0 * va.x + s1 * vb.x;
  r.y = s0 * va.y + s1 * vb.y;
  r.z = s0 * va.z + s1 * vb.z;
  r.w = s0 * va.w + s1 * vb.w;
  *reinterpret_cast<float4*>(f_t + ((long)(b * 3 + jj) * PIXN + p) * 96 + c4 * 4) = r;
}

// ---------------- host ----------------
extern "C" void kernel_launch(void* const* d_in, const int* in_sizes, int n_in,
                              void* d_out, int out_size, void* d_ws, size_t ws_size,
                              hipStream_t stream) {
  const float* fea = (const float*)d_in[0];
  const float* cf_w = (const float*)d_in[1];
  const float* cf_b = (const float*)d_in[2];
  const float* wq = (const float*)d_in[3];
  const float* bq = (const float*)d_in[4];
  const float* wk = (const float*)d_in[5];
  const float* bk = (const float*)d_in[6];
  const float* wv = (const float*)d_in[7];
  const float* bv = (const float*)d_in[8];
  const float* oc1_w = (const float*)d_in[9];
  const float* oc1_b = (const float*)d_in[10];
  const float* oc2_w = (const float*)d_in[11];
  const float* oc2_b = (const float*)d_in[12];
  const float* om_w = (const float*)d_in[13];
  const float* om_b = (const float*)d_in[14];
  const float* cl_w = (const float*)d_in[15];
  const float* cl_b = (const float*)d_in[16];

  float* ws = (float*)d_ws;
  float* T0 = ws;                       // 55296   cf_w^T
  float* T1 = T0 + 55296;               // 165888  oc1_w^T
  float* T2 = T1 + 165888;              // 82944   oc2_w^T
  float* T3 = T2 + 82944;               // 186624  om_w^T
  float* T4 = T3 + 186624;              // 55296   cl_w^T
  float* WQKV = T4 + 55296;             // 27648
  float* BQKV = WQKV + 27648;           // 288
  float* emb_t = BQKV + 288;            // 4718592 (reused as f_t)
  float* qkv_t = emb_t + 4718592;       // 14155776
  float* off1_t = qkv_t + 14155776;     // 1572864
  float* off2_t = off1_t + 1572864;     // 1572864
  float* om_t = off2_t + 1572864;       // 3538944
  float* w_buf = om_t + 3538944;        // 98304
  float* vre_buf = w_buf + 98304;       // 9437184
  float* f_t = emb_t;                   // alias: emb dead after qkv projection

  wtrans_k<<<(55296 + 255) / 256, 256, 0, stream>>>(cf_w, T0, 64, 96, 55296);
  wtrans_k<<<(165888 + 255) / 256, 256, 0, stream>>>(oc1_w, T1, 192, 96, 165888);
  wtrans_k<<<(82944 + 255) / 256, 256, 0, stream>>>(oc2_w, T2, 96, 96, 82944);
  wtrans_k<<<(186624 + 255) / 256, 256, 0, stream>>>(om_w, T3, 96, 216, 186624);
  wtrans_k<<<(55296 + 255) / 256, 256, 0, stream>>>(cl_w, T4, 96, 64, 55296);
  qkvprep_k<<<(27648 + 255) / 256, 256, 0, stream>>>(wq, wk, wv, bq, bk, bv, WQKV, BQKV);

  // emb = conv3x3(x, cf_w) from NCHW input -> NHWC
  conv3x3_k<64, 96, ACT_NONE, true, false><<<dim3(64, 12), 256, 0, stream>>>(
      fea, (long)64 * PIXN, 0, nullptr, 0, 0, 64,
      T0, cf_b, emb_t, (long)PIXN * 96, nullptr, 0);
  // q,k,v 1x1 projections -> (12,4096,288)
  gemm1x1_k<<<dim3(64, 12), 256, 0, stream>>>(emb_t, WQKV, BQKV, qkv_t);

  int pairIdx = 0;
  for (int jjv = 0; jjv < 3; ++jjv) {
    for (int iiv = 0; iiv < 3; ++iiv) {
      if (iiv == jjv) continue;
      // off1 = lrelu(conv3x3(concat(q[jj], k[ii]), oc1_w))
      conv3x3_k<192, 96, ACT_LRELU, false, false><<<dim3(64, 4), 256, 0, stream>>>(
          qkv_t + (long)jjv * PIXN * 288, (long)3 * PIXN * 288, 288,
          qkv_t + (long)iiv * PIXN * 288 + 96, (long)3 * PIXN * 288, 288, 96,
          T1, oc1_b, off1_t, (long)PIXN * 96, nullptr, 0);
      // off2 = lrelu(conv3x3(off1, oc2_w))
      conv3x3_k<96, 96, ACT_LRELU, false, false><<<dim3(64, 4), 256, 0, stream>>>(
          off1_t, (long)PIXN * 96, 96, nullptr, 0, 0, 96,
          T2, oc2_b, off2_t, (long)PIXN * 96, nullptr, 0);
      // om = conv3x3(off2, om_w)  (shared by k- and v-sampling)
      conv3x3_k<96, 216, ACT_NONE, false, false><<<dim3(64, 4), 256, 0, stream>>>(
          off2_t, (long)PIXN * 96, 96, nullptr, 0, 0, 96,
          T3, om_b, om_t, (long)PIXN * 216, nullptr, 0);
      // fused deformable sampling + rel + top2 + select
      attn_k<<<16384, 64, 0, stream>>>(qkv_t, jjv, iiv, om_t,
                                       w_buf + (long)pairIdx * 16384,
                                       vre_buf + (long)pairIdx * 16384 * 96);
      ++pairIdx;
    }
  }
  merge_k<<<4608, 256, 0, stream>>>(w_buf, vre_buf, f_t);
  // final conv + residual, NCHW output
  conv3x3_k<96, 64, ACT_NONE, false, true><<<dim3(64, 12), 256, 0, stream>>>(
      f_t, (long)PIXN * 96, 96, nullptr, 0, 0, 96,
      T4, cl_b, (float*)d_out, (long)64 * PIXN, fea, (long)64 * PIXN);
}

// Round 2
// 7169.066 us; speedup vs baseline: 2.2584x; 2.2584x over previous
//
#include <hip/hip_runtime.h>
#include <math.h>

#define PIXN 4096

enum { ACT_NONE = 0, ACT_LRELU = 1 };

// ---------------- weight prep ----------------
// wT[(tap*CIN + ci)*COUT + co] = w[(co*CIN + ci)*9 + tap]
__global__ __launch_bounds__(256) void wtrans_k(const float* __restrict__ w,
                                                float* __restrict__ wT,
                                                int CINv, int COUTv, int total) {
  int idx = blockIdx.x * 256 + threadIdx.x;
  if (idx >= total) return;
  int co = idx % COUTv;
  int t = idx / COUTv;
  int ci = t % CINv;
  int tap = t / CINv;
  wT[idx] = w[(co * CINv + ci) * 9 + tap];
}

// wT[c*288 + m*96 + e] = wm[e*96 + c];  bT[m*96+e] = bm[e]
__global__ __launch_bounds__(256) void qkvprep_k(const float* __restrict__ wq,
                                                 const float* __restrict__ wk,
                                                 const float* __restrict__ wv,
                                                 const float* __restrict__ bq,
                                                 const float* __restrict__ bk,
                                                 const float* __restrict__ bv,
                                                 float* __restrict__ wT,
                                                 float* __restrict__ bT) {
  int idx = blockIdx.x * 256 + threadIdx.x;
  if (idx < 96 * 288) {
    int e288 = idx % 288;
    int c = idx / 288;
    int m = e288 / 96, e = e288 % 96;
    const float* wm = (m == 0) ? wq : (m == 1) ? wk : wv;
    wT[idx] = wm[e * 96 + c];
  }
  if (idx < 288) {
    int m = idx / 96, e = idx % 96;
    const float* bm = (m == 0) ? bq : (m == 1) ? bk : bv;
    bT[idx] = bm[e];
  }
}

// ---------------- direct 3x3 conv, NHWC activations ----------------
// Block: 256 threads = 64 pixels (one row) x 4 oc-slots.
// Grid: (64 rows, n_img, n_pair*CG). CG = output-channel groups.
// wT layout: [tap][cin][oc].
// QK mode: input = concat(q[jj], k[ii]) drawn from qkv tensor, pair-derived.
template <int CIN, int COUT, int CG, int ACT, bool IN_NCHW, bool OUT_NCHW, bool QK>
__global__ __launch_bounds__(256) void conv3x3_k(
    const float* __restrict__ in, long sImg, long sPair, int ld,
    const float* __restrict__ wT, const float* __restrict__ bias,
    float* __restrict__ out, long sOutImg, long sOutPair,
    const float* __restrict__ resid) {
  constexpr int NOC4 = COUT / 4;
  constexpr int NOC4G = NOC4 / CG;      // oc4 per group (divides exactly)
  constexpr int NPS = (NOC4G + 3) / 4;  // oc4 per slot within group
  constexpr int NCHUNK = CIN / 16;
  const int y = blockIdx.x;
  const int img = blockIdx.y;
  const int pz = blockIdx.z;
  const int pair = pz / CG;
  const int cg = pz % CG;
  const int tid = threadIdx.x;
  const int pix = tid & 63;
  const int slot = tid >> 6;
  const int ocb = cg * NOC4G;

  const float* baseA;
  const float* baseB = nullptr;
  int ldv = ld;
  if constexpr (QK) {
    int jj = pair >> 1, r = pair & 1;
    int ii = (r == 0) ? (jj == 0 ? 1 : 0) : (jj == 2 ? 1 : 2);
    baseA = in + (long)(img * 3 + jj) * (PIXN * 288);
    baseB = in + (long)(img * 3 + ii) * (PIXN * 288) + 96;
    ldv = 288;
  } else {
    baseA = in + img * sImg + pair * sPair;
  }

  __shared__ float lds[3 * 66 * 17];

  float acc[NPS][4];
#pragma unroll
  for (int j = 0; j < NPS; ++j) {
    int oc4g = slot + 4 * j;
#pragma unroll
    for (int k = 0; k < 4; ++k)
      acc[j][k] = (oc4g < NOC4G) ? bias[(ocb + oc4g) * 4 + k] : 0.f;
  }

  for (int ch = 0; ch < NCHUNK; ++ch) {
    __syncthreads();
    if constexpr (IN_NCHW) {
      for (int i = tid; i < 16 * 198; i += 256) {
        int cin = i / 198;
        int pos = i - cin * 198;
        int r = pos / 66;
        int c = pos - r * 66;
        int yy = y + r - 1;
        int xx = c - 1;
        float v = 0.f;
        if ((unsigned)yy < 64u && (unsigned)xx < 64u)
          v = baseA[(long)(ch * 16 + cin) * PIXN + yy * 64 + xx];
        lds[pos * 17 + cin] = v;
      }
    } else {
      for (int i = tid; i < 4 * 198; i += 256) {
        int c4 = i & 3;
        int pos = i >> 2;
        int r = pos / 66;
        int c = pos - r * 66;
        int yy = y + r - 1;
        int xx = c - 1;
        float4 v = make_float4(0.f, 0.f, 0.f, 0.f);
        int cing = ch * 16 + c4 * 4;
        if ((unsigned)yy < 64u && (unsigned)xx < 64u) {
          const float* src;
          if (QK && cing >= 96)
            src = baseB + (long)(yy * 64 + xx) * 288 + (cing - 96);
          else
            src = baseA + (long)(yy * 64 + xx) * ldv + cing;
          v = *reinterpret_cast<const float4*>(src);
        }
        int base = pos * 17 + c4 * 4;
        lds[base] = v.x; lds[base + 1] = v.y; lds[base + 2] = v.z; lds[base + 3] = v.w;
      }
    }
    __syncthreads();
#pragma unroll
    for (int r = 0; r < 3; ++r) {
#pragma unroll
      for (int kx = 0; kx < 3; ++kx) {
        const float* wp = wT + (long)((r * 3 + kx) * CIN + ch * 16) * COUT + (ocb + slot) * 4;
        const int lbase = (r * 66 + pix + kx) * 17;
#pragma unroll 4
        for (int cin = 0; cin < 16; ++cin) {
          float xv = lds[lbase + cin];
          const float* wpc = wp + cin * COUT;
#pragma unroll
          for (int j = 0; j < NPS; ++j) {
            if (slot + 4 * j < NOC4G) {
              float4 w4 = *reinterpret_cast<const float4*>(wpc + j * 16);
              acc[j][0] = fmaf(xv, w4.x, acc[j][0]);
              acc[j][1] = fmaf(xv, w4.y, acc[j][1]);
              acc[j][2] = fmaf(xv, w4.z, acc[j][2]);
              acc[j][3] = fmaf(xv, w4.w, acc[j][3]);
            }
          }
        }
      }
    }
  }

  const int p = y * 64 + pix;
#pragma unroll
  for (int j = 0; j < NPS; ++j) {
    int oc4g = slot + 4 * j;
    if (oc4g >= NOC4G) continue;
    int oc4 = ocb + oc4g;
    float vv[4] = {acc[j][0], acc[j][1], acc[j][2], acc[j][3]};
    if (ACT == ACT_LRELU) {
#pragma unroll
      for (int k = 0; k < 4; ++k) vv[k] = vv[k] >= 0.f ? vv[k] : 0.1f * vv[k];
    }
    if constexpr (OUT_NCHW) {
      int oc = oc4 * 4;
#pragma unroll
      for (int k = 0; k < 4; ++k) {
        long o = img * sOutImg + (long)(oc + k) * PIXN + p;
        float rsd = resid[img * (long)(64 * PIXN) + (long)(oc + k) * PIXN + p];
        out[o] = vv[k] + rsd;
      }
    } else {
      float4 v = make_float4(vv[0], vv[1], vv[2], vv[3]);
      *reinterpret_cast<float4*>(out + img * sOutImg + pair * sOutPair +
                                 (long)p * COUT + oc4 * 4) = v;
    }
  }
}

// ---------------- 1x1 qkv projection: (12,4096,96) -> (12,4096,288) ----------------
// grid (64 px-chunks, 12 imgs, 3 oc-groups of 96)
__global__ __launch_bounds__(256) void gemm1x1_k(const float* __restrict__ in,
                                                 const float* __restrict__ wT,
                                                 const float* __restrict__ bias,
                                                 float* __restrict__ out) {
  const int pc = blockIdx.x;
  const int img = blockIdx.y;
  const int cg = blockIdx.z;
  const int tid = threadIdx.x;
  const int pix = tid & 63;
  const int slot = tid >> 6;
  __shared__ float lds[64 * 97];
  for (int i = tid; i < 64 * 24; i += 256) {
    int pi = i / 24, c4 = i - pi * 24;
    float4 v = *reinterpret_cast<const float4*>(
        in + ((long)img * PIXN + pc * 64 + pi) * 96 + c4 * 4);
    int base = pi * 97 + c4 * 4;
    lds[base] = v.x; lds[base + 1] = v.y; lds[base + 2] = v.z; lds[base + 3] = v.w;
  }
  __syncthreads();
  float acc[6][4];
#pragma unroll
  for (int j = 0; j < 6; ++j) {
    int oc4 = cg * 24 + slot + 4 * j;
#pragma unroll
    for (int k = 0; k < 4; ++k) acc[j][k] = bias[oc4 * 4 + k];
  }
  for (int c = 0; c < 96; ++c) {
    float xv = lds[pix * 97 + c];
    const float* wp = wT + c * 288 + (cg * 24 + slot) * 4;
#pragma unroll
    for (int j = 0; j < 6; ++j) {
      float4 w4 = *reinterpret_cast<const float4*>(wp + j * 16);
      acc[j][0] = fmaf(xv, w4.x, acc[j][0]);
      acc[j][1] = fmaf(xv, w4.y, acc[j][1]);
      acc[j][2] = fmaf(xv, w4.z, acc[j][2]);
      acc[j][3] = fmaf(xv, w4.w, acc[j][3]);
    }
  }
  float* orow = out + ((long)img * PIXN + pc * 64 + pix) * 288;
#pragma unroll
  for (int j = 0; j < 6; ++j) {
    float4 v = make_float4(acc[j][0], acc[j][1], acc[j][2], acc[j][3]);
    *reinterpret_cast<float4*>(orow + (cg * 24 + slot + 4 * j) * 4) = v;
  }
}

// ---------------- fused deformable sample + top2 attention ----------------
// s_om: [0..71]=off_y (g*9+n), [72..143]=off_x, [144..215]=sigmoid mask
__device__ __forceinline__ float dsampK(const float* __restrict__ kimg,
                                        const float* __restrict__ s_om,
                                        int g, int n, int y, int x, int c) {
  float oy = s_om[g * 9 + n];
  float ox = s_om[72 + g * 9 + n];
  float m = s_om[144 + g * 9 + n];
  float py = oy + (float)(y + n / 3 - 1);
  float px = ox + (float)(x + n % 3 - 1);
  float y0 = floorf(py), x0 = floorf(px);
  float wy = py - y0, wx = px - x0;
  float acc = 0.f;
#pragma unroll
  for (int dy = 0; dy < 2; ++dy) {
#pragma unroll
    for (int dx = 0; dx < 2; ++dx) {
      float yc = y0 + dy, xc = x0 + dx;
      if (yc >= 0.f && yc < 64.f && xc >= 0.f && xc < 64.f) {
        float w = (dy ? wy : 1.f - wy) * (dx ? wx : 1.f - wx);
        acc = fmaf(w, kimg[(long)((int)yc * 64 + (int)xc) * 288 + 96 + c], acc);
      }
    }
  }
  return acc * m;
}

__device__ __forceinline__ float2 dsamp2(const float* __restrict__ kimg,
                                         const float* __restrict__ s_om,
                                         int g, int n, int y, int x, int c) {
  float oy = s_om[g * 9 + n];
  float ox = s_om[72 + g * 9 + n];
  float m = s_om[144 + g * 9 + n];
  float py = oy + (float)(y + n / 3 - 1);
  float px = ox + (float)(x + n % 3 - 1);
  float y0 = floorf(py), x0 = floorf(px);
  float wy = py - y0, wx = px - x0;
  float aK = 0.f, aV = 0.f;
#pragma unroll
  for (int dy = 0; dy < 2; ++dy) {
#pragma unroll
    for (int dx = 0; dx < 2; ++dx) {
      float yc = y0 + dy, xc = x0 + dx;
      if (yc >= 0.f && yc < 64.f && xc >= 0.f && xc < 64.f) {
        float w = (dy ? wy : 1.f - wy) * (dx ? wx : 1.f - wx);
        const float* pp = kimg + (long)((int)yc * 64 + (int)xc) * 288 + 96 + c;
        aK = fmaf(w, pp[0], aK);
        aV = fmaf(w, pp[96], aV);
      }
    }
  }
  return make_float2(aK * m, aV * m);
}

// grid (16384 = b*4096+p, 6 = pair)
__global__ __launch_bounds__(64) void attn_k(const float* __restrict__ qkv,
                                             const float* __restrict__ om,
                                             float* __restrict__ w_buf,
                                             float* __restrict__ vre) {
  const int bp = blockIdx.x;
  const int pair = blockIdx.y;
  const int jj = pair >> 1, rr = pair & 1;
  const int ii = (rr == 0) ? (jj == 0 ? 1 : 0) : (jj == 2 ? 1 : 2);
  const int b = bp >> 12;
  const int p = bp & 4095;
  const int y = p >> 6, x = p & 63;
  const int lane = threadIdx.x;
  __shared__ float s_om[216];
  const float* omrow = om + (long)pair * 4 * PIXN * 216 + (long)bp * 216;
  for (int i = lane; i < 216; i += 64) {
    float v = omrow[i];
    if (i >= 144) v = 1.f / (1.f + expf(-v));
    s_om[i] = v;
  }
  __syncthreads();
  const float* qrow = qkv + ((long)(b * 3 + jj) * PIXN + p) * 288;
  const float* kimg = qkv + (long)(b * 3 + ii) * PIXN * 288;
  float q0 = qrow[lane];
  float q1 = 0.f;
  if (lane < 32) q1 = qrow[64 + lane];
  const int c0 = lane, g0 = lane / 12;
  const int c1 = 64 + lane, g1 = (64 + lane) / 12;

  float rel[9];
#pragma unroll
  for (int n = 0; n < 9; ++n) {
    float part = q0 * dsampK(kimg, s_om, g0, n, y, x, c0);
    if (lane < 32) part = fmaf(q1, dsampK(kimg, s_om, g1, n, y, x, c1), part);
#pragma unroll
    for (int off = 32; off > 0; off >>= 1) part += __shfl_xor(part, off, 64);
    rel[n] = part;
  }
  int i0 = 0; float v0 = rel[0];
#pragma unroll
  for (int n = 1; n < 9; ++n) if (rel[n] > v0) { v0 = rel[n]; i0 = n; }
  int i1 = 0; float v1 = -3.4e38f;
#pragma unroll
  for (int n = 0; n < 9; ++n) if (n != i0 && rel[n] > v1) { v1 = rel[n]; i1 = n; }
  float e = expf(v1 - v0);
  float cw0 = 1.f / (1.f + e);
  float cw1 = e * cw0;

  float2 a0 = dsamp2(kimg, s_om, g0, i0, y, x, c0);
  float2 a1 = dsamp2(kimg, s_om, g0, i1, y, x, c0);
  float kup = cw0 * a0.x + cw1 * a1.x;
  float vr = cw0 * a0.y + cw1 * a1.y;
  float wpart = q0 * kup;
  vre[((long)pair * 16384 + bp) * 96 + c0] = vr;
  if (lane < 32) {
    float2 b0 = dsamp2(kimg, s_om, g1, i0, y, x, c1);
    float2 b1 = dsamp2(kimg, s_om, g1, i1, y, x, c1);
    float kup1 = cw0 * b0.x + cw1 * b1.x;
    float vre1 = cw0 * b0.y + cw1 * b1.y;
    wpart = fmaf(q1, kup1, wpart);
    vre[((long)pair * 16384 + bp) * 96 + c1] = vre1;
  }
#pragma unroll
  for (int off = 32; off > 0; off >>= 1) wpart += __shfl_xor(wpart, off, 64);
  if (lane == 0) w_buf[(long)pair * 16384 + bp] = wpart;
}

// ---------------- merge: softmax over the 2 source frames ----------------
__global__ __launch_bounds__(256) void merge_k(const float* __restrict__ w_buf,
                                               const float* __restrict__ vre,
                                               float* __restrict__ f_t) {
  long idx = (long)blockIdx.x * 256 + threadIdx.x;
  const long TOT = (long)4 * 3 * PIXN * 24;
  if (idx >= TOT) return;
  int c4 = idx % 24;
  long t = idx / 24;
  int p = t % PIXN;
  long t2 = t / PIXN;
  int jj = t2 % 3;
  int b = (int)(t2 / 3);
  long bpi = (long)b * PIXN + p;
  int pr0 = jj * 2, pr1 = jj * 2 + 1;
  float w0 = w_buf[(long)pr0 * 16384 + bpi];
  float w1 = w_buf[(long)pr1 * 16384 + bpi];
  float mx = fmaxf(w0, w1);
  float e0 = expf(w0 - mx), e1 = expf(w1 - mx);
  float inv = 1.f / (e0 + e1);
  float s0 = e0 * inv, s1 = e1 * inv;
  float4 va = *reinterpret_cast<const float4*>(vre + ((long)pr0 * 16384 + bpi) * 96 + c4 * 4);
  float4 vb = *reinterpret_cast<const float4*>(vre + ((long)pr1 * 16384 + bpi) * 96 + c4 * 4);
  float4 r;
  r.x = s0 * va.x + s1 * vb.x;
  r.y = s0 * va.y + s1 * vb.y;
  r.z = s0 * va.z + s1 * vb.z;
  r.w = s0 * va.w + s1 * vb.w;
  *reinterpret_cast<float4*>(f_t + ((long)(b * 3 + jj) * PIXN + p) * 96 + c4 * 4) = r;
}

// ---------------- host ----------------
extern "C" void kernel_launch(void* const* d_in, const int* in_sizes, int n_in,
                              void* d_out, int out_size, void* d_ws, size_t ws_size,
                              hipStream_t stream) {
  const float* fea = (const float*)d_in[0];
  const float* cf_w = (const float*)d_in[1];
  const float* cf_b = (const float*)d_in[2];
  const float* wq = (const float*)d_in[3];
  const float* bq = (const float*)d_in[4];
  const float* wk = (const float*)d_in[5];
  const float* bk = (const float*)d_in[6];
  const float* wv = (const float*)d_in[7];
  const float* bv = (const float*)d_in[8];
  const float* oc1_w = (const float*)d_in[9];
  const float* oc1_b = (const float*)d_in[10];
  const float* oc2_w = (const float*)d_in[11];
  const float* oc2_b = (const float*)d_in[12];
  const float* om_w = (const float*)d_in[13];
  const float* om_b = (const float*)d_in[14];
  const float* cl_w = (const float*)d_in[15];
  const float* cl_b = (const float*)d_in[16];

  float* ws = (float*)d_ws;
  float* T0 = ws;                        // 55296   cf_w^T
  float* T1 = T0 + 55296;                // 165888  oc1_w^T
  float* T2 = T1 + 165888;               // 82944   oc2_w^T
  float* T3 = T2 + 82944;                // 186624  om_w^T
  float* T4 = T3 + 186624;               // 55296   cl_w^T
  float* WQKV = T4 + 55296;              // 27648
  float* BQKV = WQKV + 27648;            // 288
  float* emb_t = BQKV + 288;             // 4,718,592 (f_t alias)
  float* qkv_t = emb_t + 4718592;        // 14,155,776
  float* reg1 = qkv_t + 14155776;        // 21,233,664: off1 (first 9.4M) then om (full)
  float* reg2 = reg1 + 21233664;         // 9,437,184: off2, later vre
  float* w_buf = reg2 + 9437184;         // 98,304
  float* off1_t = reg1;
  float* om_t = reg1;                    // overlays dead off1
  float* off2_t = reg2;
  float* vre_buf = reg2;                 // overlays dead off2
  float* f_t = emb_t;                    // overlays dead emb

  wtrans_k<<<(55296 + 255) / 256, 256, 0, stream>>>(cf_w, T0, 64, 96, 55296);
  wtrans_k<<<(165888 + 255) / 256, 256, 0, stream>>>(oc1_w, T1, 192, 96, 165888);
  wtrans_k<<<(82944 + 255) / 256, 256, 0, stream>>>(oc2_w, T2, 96, 96, 82944);
  wtrans_k<<<(186624 + 255) / 256, 256, 0, stream>>>(om_w, T3, 96, 216, 186624);
  wtrans_k<<<(55296 + 255) / 256, 256, 0, stream>>>(cl_w, T4, 96, 64, 55296);
  qkvprep_k<<<(27648 + 255) / 256, 256, 0, stream>>>(wq, wk, wv, bq, bk, bv, WQKV, BQKV);

  // emb = conv3x3(x, cf_w): NCHW input -> NHWC, 2 oc-groups
  conv3x3_k<64, 96, 2, ACT_NONE, true, false, false><<<dim3(64, 12, 2), 256, 0, stream>>>(
      fea, (long)64 * PIXN, 0, 0, T0, cf_b, emb_t, (long)PIXN * 96, 0, nullptr);
  // qkv 1x1 projections, 3 oc-groups
  gemm1x1_k<<<dim3(64, 12, 3), 256, 0, stream>>>(emb_t, WQKV, BQKV, qkv_t);

  // off1 for ALL 6 pairs: concat(q[jj],k[ii]) -> 96, 2 oc-groups -> grid.z = 12
  conv3x3_k<192, 96, 2, ACT_LRELU, false, false, true><<<dim3(64, 4, 12), 256, 0, stream>>>(
      qkv_t, 0, 0, 288, T1, oc1_b, off1_t, (long)PIXN * 96, (long)4 * PIXN * 96, nullptr);
  // off2 for all pairs
  conv3x3_k<96, 96, 2, ACT_LRELU, false, false, false><<<dim3(64, 4, 12), 256, 0, stream>>>(
      off1_t, (long)PIXN * 96, (long)4 * PIXN * 96, 96, T2, oc2_b,
      off2_t, (long)PIXN * 96, (long)4 * PIXN * 96, nullptr);
  // om for all pairs, 3 oc-groups -> grid.z = 18
  conv3x3_k<96, 216, 3, ACT_NONE, false, false, false><<<dim3(64, 4, 18), 256, 0, stream>>>(
      off2_t, (long)PIXN * 96, (long)4 * PIXN * 96, 96, T3, om_b,
      om_t, (long)PIXN * 216, (long)4 * PIXN * 216, nullptr);
  // fused deformable sampling + rel + top2 + select, all pairs
  attn_k<<<dim3(16384, 6), 64, 0, stream>>>(qkv_t, om_t, w_buf, vre_buf);

  merge_k<<<4608, 256, 0, stream>>>(w_buf, vre_buf, f_t);
  // final conv + residual, NCHW output, 2 oc-groups
  conv3x3_k<96, 64, 2, ACT_NONE, false, true, false><<<dim3(64, 12, 2), 256, 0, stream>>>(
      f_t, (long)PIXN * 96, 0, 96, T4, cl_b, (float*)d_out, (long)64 * PIXN, 0, fea);
}

// Round 5
// 2186.430 us; speedup vs baseline: 7.4051x; 3.2789x over previous
//
#include <hip/hip_runtime.h>
#include <math.h>

#define PIXN 4096

typedef _Float16 f16;

__device__ __forceinline__ f16 f2h(float f) { return (f16)f; }
__device__ __forceinline__ float h2f(f16 h) { return (float)h; }

enum { ACT_NONE = 0, ACT_LRELU = 1 };
enum { IN_NCHW = 0, IN_FLAT = 1 };
enum { OUT_FLAT = 0, OUT_NCHWRES = 1 };

// ---------------- weight prep ----------------
// wT[(tap*CIN + ci)*COUT + co] = w[(co*CIN + ci)*9 + tap]
__global__ __launch_bounds__(256) void wtrans_k(const float* __restrict__ w,
                                                float* __restrict__ wT,
                                                int CINv, int COUTv, int total) {
  int idx = blockIdx.x * 256 + threadIdx.x;
  if (idx >= total) return;
  int co = idx % COUTv;
  int t = idx / COUTv;
  int ci = t % CINv;
  int tap = t / CINv;
  wT[idx] = w[(co * CINv + ci) * 9 + tap];
}

// wT[c*288 + m*96 + e] = wm[e*96 + c];  bT[m*96+e] = bm[e]
__global__ __launch_bounds__(256) void qkvprep_k(const float* __restrict__ wq,
                                                 const float* __restrict__ wk,
                                                 const float* __restrict__ wv,
                                                 const float* __restrict__ bq,
                                                 const float* __restrict__ bk,
                                                 const float* __restrict__ bv,
                                                 float* __restrict__ wT,
                                                 float* __restrict__ bT) {
  int idx = blockIdx.x * 256 + threadIdx.x;
  if (idx < 96 * 288) {
    int e288 = idx % 288;
    int c = idx / 288;
    int m = e288 / 96, e = e288 % 96;
    const float* wm = (m == 0) ? wq : (m == 1) ? wk : wv;
    wT[idx] = wm[e * 96 + c];
  }
  if (idx < 288) {
    int m = idx / 96, e = idx % 96;
    const float* bm = (m == 0) ? bq : (m == 1) ? bk : bv;
    bT[idx] = bm[e];
  }
}

// ---------------- fp32 3x3 conv, GEMV-style: thread = 1 pixel, scalar weights ----------------
// Block 256 = 4 waves; wave wv = output row y0+wv (y0 = 4*blockIdx.x), lane = x.
// acc[NOCG] per thread. Weight addresses are thread-uniform -> s_load (scalar pipe).
// LDS tile: 6 rows x 66 px x 16 cin, stride 17 (2 lanes/bank, conflict-free).
template <int CIN, int COUT, int CG, int ACT, int IMODE, int OMODE, bool DUAL>
__global__ __launch_bounds__(256) void conv3x3f(
    const float* __restrict__ in,
    const float* __restrict__ wT,    // [tap][CIN][COUT]
    const float* __restrict__ bias,
    float* __restrict__ out,
    const float* __restrict__ resid) {
  constexpr int NOCG = COUT / CG;
  constexpr int NCH = CIN / 16;
  const int y0 = blockIdx.x * 4;
  const int iz = blockIdx.y;
  const int cg = blockIdx.z;
  const int tid = threadIdx.x;
  const int x = tid & 63;
  const int wv = tid >> 6;

  __shared__ float lds[6 * 66 * 17];

  const float* baseA;
  const float* baseB = nullptr;
  if constexpr (DUAL) {
    int pair = iz >> 2, b = iz & 3;
    int jj = pair >> 1, rr = pair & 1;
    int ii = (rr == 0) ? (jj == 0 ? 1 : 0) : (jj == 2 ? 1 : 2);
    baseA = in + (long)(b * 3 + jj) * (PIXN * 288);        // q channels
    baseB = in + (long)(b * 3 + ii) * (PIXN * 288) + 96;   // k channels
  } else if constexpr (IMODE == IN_NCHW) {
    baseA = in + (long)iz * (CIN * PIXN);
  } else {
    baseA = in + (long)iz * (PIXN * CIN);
  }

  float acc[NOCG];
#pragma unroll
  for (int j = 0; j < NOCG; ++j) acc[j] = bias[cg * NOCG + j];

#pragma unroll 1
  for (int ch = 0; ch < NCH; ++ch) {
    __syncthreads();
    if constexpr (IMODE == IN_NCHW) {
      for (int i = tid; i < 6336; i += 256) {   // 16 cin * 396 px
        int t = i % 396, cin = i / 396;
        int row = t / 66, px = t - row * 66;
        int yy = y0 - 1 + row, xx = px - 1;
        float v = 0.f;
        if ((unsigned)yy < 64u && (unsigned)xx < 64u)
          v = baseA[(long)(ch * 16 + cin) * PIXN + yy * 64 + xx];
        lds[t * 17 + cin] = v;
      }
    } else {
      for (int i = tid; i < 1584; i += 256) {   // 396 px * 4 float4
        int c4 = i & 3, t = i >> 2;
        int row = t / 66, px = t - row * 66;
        int yy = y0 - 1 + row, xx = px - 1;
        float4 v = make_float4(0.f, 0.f, 0.f, 0.f);
        if ((unsigned)yy < 64u && (unsigned)xx < 64u) {
          const float* src;
          if constexpr (DUAL) {
            int cing = ch * 16 + c4 * 4;
            if (cing < 96) src = baseA + (long)(yy * 64 + xx) * 288 + cing;
            else           src = baseB + (long)(yy * 64 + xx) * 288 + (cing - 96);
          } else {
            src = baseA + (long)(yy * 64 + xx) * CIN + ch * 16 + c4 * 4;
          }
          v = *reinterpret_cast<const float4*>(src);
        }
        int b0 = t * 17 + c4 * 4;
        lds[b0] = v.x; lds[b0 + 1] = v.y; lds[b0 + 2] = v.z; lds[b0 + 3] = v.w;
      }
    }
    __syncthreads();

#pragma unroll
    for (int r = 0; r < 3; ++r) {
#pragma unroll
      for (int kx = 0; kx < 3; ++kx) {
        const float* wp = wT + ((long)((r * 3 + kx) * CIN + ch * 16)) * COUT + cg * NOCG;
        const int lb = ((wv + r) * 66 + x + kx) * 17;
#pragma unroll 2
        for (int cin = 0; cin < 16; ++cin) {
          float xv = lds[lb + cin];
          const float* wpc = wp + cin * COUT;   // thread-uniform -> s_load
#pragma unroll
          for (int j = 0; j < NOCG; ++j)
            acc[j] = fmaf(xv, wpc[j], acc[j]);
        }
      }
    }
  }

  const int yo = y0 + wv;
#pragma unroll
  for (int j = 0; j < NOCG; ++j) {
    if (ACT == ACT_LRELU) acc[j] = acc[j] >= 0.f ? acc[j] : 0.1f * acc[j];
  }
  if constexpr (OMODE == OUT_FLAT) {
    float* orow = out + ((long)iz * PIXN + yo * 64 + x) * COUT + cg * NOCG;
#pragma unroll
    for (int j4 = 0; j4 < NOCG / 4; ++j4) {
      float4 v = make_float4(acc[j4 * 4], acc[j4 * 4 + 1], acc[j4 * 4 + 2], acc[j4 * 4 + 3]);
      *reinterpret_cast<float4*>(orow + j4 * 4) = v;
    }
  } else {  // OUT_NCHWRES
#pragma unroll
    for (int j = 0; j < NOCG; ++j) {
      int oc = cg * NOCG + j;
      long oo = (long)iz * (COUT * PIXN) + (long)oc * PIXN + yo * 64 + x;
      out[oo] = acc[j] + resid[oo];
    }
  }
}

// ---------------- 1x1 qkv projection, GEMV-style ----------------
// Block 256 = 256 px; grid (16 px-blocks, 12 imgs, 3 oc-groups of 96)
__global__ __launch_bounds__(256) void gemm1x1v2(const float* __restrict__ in,
                                                 const float* __restrict__ wT,
                                                 const float* __restrict__ bias,
                                                 float* __restrict__ out) {
  const int pcb = blockIdx.x;
  const int img = blockIdx.y;
  const int cg = blockIdx.z;
  const int tid = threadIdx.x;
  __shared__ float lds[256 * 33];
  float acc[96];
#pragma unroll
  for (int j = 0; j < 96; ++j) acc[j] = bias[cg * 96 + j];
  const float* ibase = in + ((long)img * PIXN + pcb * 256) * 96;
#pragma unroll 1
  for (int cc = 0; cc < 96; cc += 32) {
    __syncthreads();
    for (int i = tid; i < 2048; i += 256) {   // 256 px * 8 float4
      int px = i >> 3, c4 = i & 7;
      float4 v = *reinterpret_cast<const float4*>(ibase + (long)px * 96 + cc + c4 * 4);
      int b0 = px * 33 + c4 * 4;
      lds[b0] = v.x; lds[b0 + 1] = v.y; lds[b0 + 2] = v.z; lds[b0 + 3] = v.w;
    }
    __syncthreads();
#pragma unroll 2
    for (int c = 0; c < 32; ++c) {
      float xv = lds[tid * 33 + c];
      const float* wp = wT + (long)(cc + c) * 288 + cg * 96;   // uniform -> s_load
#pragma unroll
      for (int j = 0; j < 96; ++j) acc[j] = fmaf(xv, wp[j], acc[j]);
    }
  }
  float* orow = out + ((long)img * PIXN + pcb * 256 + tid) * 288 + cg * 96;
#pragma unroll
  for (int j4 = 0; j4 < 24; ++j4) {
    float4 v = make_float4(acc[j4 * 4], acc[j4 * 4 + 1], acc[j4 * 4 + 2], acc[j4 * 4 + 3]);
    *reinterpret_cast<float4*>(orow + j4 * 4) = v;
  }
}

// ---------------- fused deformable sample + top2 attention (fp32) ----------------
__device__ __forceinline__ float dsampK(const float* __restrict__ kimg,
                                        const float* __restrict__ s_om,
                                        int g, int n, int y, int x, int c) {
  float oy = s_om[g * 9 + n];
  float ox = s_om[72 + g * 9 + n];
  float m = s_om[144 + g * 9 + n];
  float py = oy + (float)(y + n / 3 - 1);
  float px = ox + (float)(x + n % 3 - 1);
  float y0 = floorf(py), x0 = floorf(px);
  float wy = py - y0, wx = px - x0;
  float acc = 0.f;
#pragma unroll
  for (int dy = 0; dy < 2; ++dy) {
#pragma unroll
    for (int dx = 0; dx < 2; ++dx) {
      float yc = y0 + dy, xc = x0 + dx;
      if (yc >= 0.f && yc < 64.f && xc >= 0.f && xc < 64.f) {
        float w = (dy ? wy : 1.f - wy) * (dx ? wx : 1.f - wx);
        acc = fmaf(w, kimg[(long)((int)yc * 64 + (int)xc) * 288 + 96 + c], acc);
      }
    }
  }
  return acc * m;
}

__device__ __forceinline__ float2 dsamp2(const float* __restrict__ kimg,
                                         const float* __restrict__ s_om,
                                         int g, int n, int y, int x, int c) {
  float oy = s_om[g * 9 + n];
  float ox = s_om[72 + g * 9 + n];
  float m = s_om[144 + g * 9 + n];
  float py = oy + (float)(y + n / 3 - 1);
  float px = ox + (float)(x + n % 3 - 1);
  float y0 = floorf(py), x0 = floorf(px);
  float wy = py - y0, wx = px - x0;
  float aK = 0.f, aV = 0.f;
#pragma unroll
  for (int dy = 0; dy < 2; ++dy) {
#pragma unroll
    for (int dx = 0; dx < 2; ++dx) {
      float yc = y0 + dy, xc = x0 + dx;
      if (yc >= 0.f && yc < 64.f && xc >= 0.f && xc < 64.f) {
        float w = (dy ? wy : 1.f - wy) * (dx ? wx : 1.f - wx);
        const float* pp = kimg + (long)((int)yc * 64 + (int)xc) * 288 + 96 + c;
        aK = fmaf(w, pp[0], aK);
        aV = fmaf(w, pp[96], aV);
      }
    }
  }
  return make_float2(aK * m, aV * m);
}

// grid (16384 = b*4096+p, 6 = pair); om fp32; vre out f16 (post-selection)
__global__ __launch_bounds__(64) void attn_k(const float* __restrict__ qkv,
                                             const float* __restrict__ om,
                                             float* __restrict__ w_buf,
                                             f16* __restrict__ vre) {
  const int bp = blockIdx.x;
  const int pair = blockIdx.y;
  const int jj = pair >> 1, rr = pair & 1;
  const int ii = (rr == 0) ? (jj == 0 ? 1 : 0) : (jj == 2 ? 1 : 2);
  const int b = bp >> 12;
  const int p = bp & 4095;
  const int y = p >> 6, x = p & 63;
  const int lane = threadIdx.x;
  __shared__ float s_om[216];
  const float* omrow = om + ((long)pair * 4 * PIXN + bp) * 216;
  for (int i = lane; i < 216; i += 64) {
    float v = omrow[i];
    if (i >= 144) v = 1.f / (1.f + expf(-v));
    s_om[i] = v;
  }
  __syncthreads();
  const float* qrow = qkv + ((long)(b * 3 + jj) * PIXN + p) * 288;
  const float* kimg = qkv + (long)(b * 3 + ii) * PIXN * 288;
  float q0 = qrow[lane];
  float q1 = 0.f;
  if (lane < 32) q1 = qrow[64 + lane];
  const int c0 = lane, g0 = lane / 12;
  const int c1 = 64 + lane, g1 = (64 + lane) / 12;

  float rel[9];
#pragma unroll
  for (int n = 0; n < 9; ++n) {
    float part = q0 * dsampK(kimg, s_om, g0, n, y, x, c0);
    if (lane < 32) part = fmaf(q1, dsampK(kimg, s_om, g1, n, y, x, c1), part);
#pragma unroll
    for (int off = 32; off > 0; off >>= 1) part += __shfl_xor(part, off, 64);
    rel[n] = part;
  }
  int i0 = 0; float v0 = rel[0];
#pragma unroll
  for (int n = 1; n < 9; ++n) if (rel[n] > v0) { v0 = rel[n]; i0 = n; }
  int i1 = 0; float v1 = -3.4e38f;
#pragma unroll
  for (int n = 0; n < 9; ++n) if (n != i0 && rel[n] > v1) { v1 = rel[n]; i1 = n; }
  float e = expf(v1 - v0);
  float cw0 = 1.f / (1.f + e);
  float cw1 = e * cw0;

  float2 a0 = dsamp2(kimg, s_om, g0, i0, y, x, c0);
  float2 a1 = dsamp2(kimg, s_om, g0, i1, y, x, c0);
  float kup = cw0 * a0.x + cw1 * a1.x;
  float vr = cw0 * a0.y + cw1 * a1.y;
  float wpart = q0 * kup;
  vre[((long)pair * 16384 + bp) * 96 + c0] = f2h(vr);
  if (lane < 32) {
    float2 b0 = dsamp2(kimg, s_om, g1, i0, y, x, c1);
    float2 b1 = dsamp2(kimg, s_om, g1, i1, y, x, c1);
    float kup1 = cw0 * b0.x + cw1 * b1.x;
    float vre1 = cw0 * b0.y + cw1 * b1.y;
    wpart = fmaf(q1, kup1, wpart);
    vre[((long)pair * 16384 + bp) * 96 + c1] = f2h(vre1);
  }
#pragma unroll
  for (int off = 32; off > 0; off >>= 1) wpart += __shfl_xor(wpart, off, 64);
  if (lane == 0) w_buf[(long)pair * 16384 + bp] = wpart;
}

// ---------------- merge: softmax over the 2 source frames -> f_t fp32 flat ----------------
__global__ __launch_bounds__(256) void merge_k(const float* __restrict__ w_buf,
                                               const f16* __restrict__ vre,
                                               float* __restrict__ f_t) {
  long idx = (long)blockIdx.x * 256 + threadIdx.x;
  const long TOT = (long)4 * 3 * PIXN * 24;
  if (idx >= TOT) return;
  int c4 = idx % 24;
  long t = idx / 24;
  int p = t % PIXN;
  long t2 = t / PIXN;
  int jj = t2 % 3;
  int b = (int)(t2 / 3);
  long bpi = (long)b * PIXN + p;
  int pr0 = jj * 2, pr1 = jj * 2 + 1;
  float w0 = w_buf[(long)pr0 * 16384 + bpi];
  float w1 = w_buf[(long)pr1 * 16384 + bpi];
  float mx = fmaxf(w0, w1);
  float e0 = expf(w0 - mx), e1 = expf(w1 - mx);
  float inv = 1.f / (e0 + e1);
  float s0 = e0 * inv, s1 = e1 * inv;
  const f16* va = &vre[((long)pr0 * 16384 + bpi) * 96 + c4 * 4];
  const f16* vb = &vre[((long)pr1 * 16384 + bpi) * 96 + c4 * 4];
  float4 r;
  r.x = s0 * h2f(va[0]) + s1 * h2f(vb[0]);
  r.y = s0 * h2f(va[1]) + s1 * h2f(vb[1]);
  r.z = s0 * h2f(va[2]) + s1 * h2f(vb[2]);
  r.w = s0 * h2f(va[3]) + s1 * h2f(vb[3]);
  *reinterpret_cast<float4*>(f_t + ((long)(b * 3 + jj) * PIXN + p) * 96 + c4 * 4) = r;
}

// ---------------- host ----------------
extern "C" void kernel_launch(void* const* d_in, const int* in_sizes, int n_in,
                              void* d_out, int out_size, void* d_ws, size_t ws_size,
                              hipStream_t stream) {
  const float* fea = (const float*)d_in[0];
  const float* cf_w = (const float*)d_in[1];
  const float* cf_b = (const float*)d_in[2];
  const float* wq = (const float*)d_in[3];
  const float* bq = (const float*)d_in[4];
  const float* wk = (const float*)d_in[5];
  const float* bk = (const float*)d_in[6];
  const float* wv = (const float*)d_in[7];
  const float* bv = (const float*)d_in[8];
  const float* oc1_w = (const float*)d_in[9];
  const float* oc1_b = (const float*)d_in[10];
  const float* oc2_w = (const float*)d_in[11];
  const float* oc2_b = (const float*)d_in[12];
  const float* om_w = (const float*)d_in[13];
  const float* om_b = (const float*)d_in[14];
  const float* cl_w = (const float*)d_in[15];
  const float* cl_b = (const float*)d_in[16];

  char* base = (char*)d_ws;
  size_t o = 0;
  auto carve = [&](size_t bytes) { char* p = base + o; o += (bytes + 255) & ~255UL; return p; };

  float* T0 = (float*)carve(55296UL * 4);    // cf  [tap][64][96]
  float* T1 = (float*)carve(165888UL * 4);   // oc1 [tap][192][96]
  float* T2 = (float*)carve(82944UL * 4);    // oc2 [tap][96][96]
  float* T3 = (float*)carve(186624UL * 4);   // om  [tap][96][216]
  float* T4 = (float*)carve(55296UL * 4);    // cl  [tap][96][64]
  float* WQKV = (float*)carve(27648UL * 4);
  float* BQKV = (float*)carve(288UL * 4);

  // R region hosts sequentially: emb (4.7M) -> off1 (9.4M) -> om (21.2M) -> f_t (4.7M)
  float* R = (float*)carve(21233664UL * 4);
  float* emb_t = R;
  float* off1_t = R;
  float* om_t = R;
  float* f_t = R;
  float* off2_t = (float*)carve(9437184UL * 4);
  float* qkv_t = (float*)carve(14155776UL * 4);
  f16* vre_b = (f16*)carve(9437184UL * 2);
  float* w_buf = (float*)carve(98304UL * 4);

  // --- weight prep ---
  wtrans_k<<<(55296 + 255) / 256, 256, 0, stream>>>(cf_w, T0, 64, 96, 55296);
  wtrans_k<<<(165888 + 255) / 256, 256, 0, stream>>>(oc1_w, T1, 192, 96, 165888);
  wtrans_k<<<(82944 + 255) / 256, 256, 0, stream>>>(oc2_w, T2, 96, 96, 82944);
  wtrans_k<<<(186624 + 255) / 256, 256, 0, stream>>>(om_w, T3, 96, 216, 186624);
  wtrans_k<<<(55296 + 255) / 256, 256, 0, stream>>>(cl_w, T4, 96, 64, 55296);
  qkvprep_k<<<(27648 + 255) / 256, 256, 0, stream>>>(wq, wk, wv, bq, bk, bv, WQKV, BQKV);

  // --- emb conv (fp32): NCHW in -> NHWC flat ---
  conv3x3f<64, 96, 2, ACT_NONE, IN_NCHW, OUT_FLAT, false><<<dim3(16, 12, 2), 256, 0, stream>>>(
      fea, T0, cf_b, emb_t, nullptr);
  // --- qkv 1x1 (fp32) ---
  gemm1x1v2<<<dim3(16, 12, 3), 256, 0, stream>>>(emb_t, WQKV, BQKV, qkv_t);

  // --- off1 (dual q/k input), off2, om for all 6 pairs x 4 batches ---
  conv3x3f<192, 96, 2, ACT_LRELU, IN_FLAT, OUT_FLAT, true><<<dim3(16, 24, 2), 256, 0, stream>>>(
      qkv_t, T1, oc1_b, off1_t, nullptr);
  conv3x3f<96, 96, 2, ACT_LRELU, IN_FLAT, OUT_FLAT, false><<<dim3(16, 24, 2), 256, 0, stream>>>(
      off1_t, T2, oc2_b, off2_t, nullptr);
  conv3x3f<96, 216, 3, ACT_NONE, IN_FLAT, OUT_FLAT, false><<<dim3(16, 24, 3), 256, 0, stream>>>(
      off2_t, T3, om_b, om_t, nullptr);

  // --- fused deformable attention (fp32 selection path) ---
  attn_k<<<dim3(16384, 6), 64, 0, stream>>>(qkv_t, om_t, w_buf, vre_b);
  merge_k<<<4608, 256, 0, stream>>>(w_buf, vre_b, f_t);

  // --- final conv + residual -> NCHW fp32 ---
  conv3x3f<96, 64, 1, ACT_NONE, IN_FLAT, OUT_NCHWRES, false><<<dim3(16, 12, 1), 256, 0, stream>>>(
      f_t, T4, cl_b, (float*)d_out, fea);
}